// Round 7
// baseline (612.617 us; speedup 1.0000x reference)
//
#include <hip/hip_runtime.h>
#include <hip/hip_fp16.h>

// VQ codebook argmin: N=32768 x K=8192 x D=256 fp32.
// f16 hi/lo split (3 MFMA terms) = fp32-exact argmin (absmax 0, R2-R6).
//
// R6: 565us, MfmaUtil 33%: B-fragment region (8MB) > 4MB XCD L2 -> streams
//     from L3 at ~13 TB/s; need 39 TB/s at full MFMA rate. 33% == 13/39.
// R7: XCD-pinned code splits: split = blockIdx & 7 (dispatch round-robins
//     XCDs) -> each XCD's 1MB B-slice is L2-resident. B then rides per-XCD
//     L2 (3.3 of 4.3 TB/s). K-loop identical to R6 (0 conflicts, no LDS).

#define N_Q   32768
#define BF_OFF 16777216u   // halves: aF 32MB | bF 8MB | cbs | partials

typedef _Float16 half8 __attribute__((ext_vector_type(8)));
typedef float    f32x16 __attribute__((ext_vector_type(16)));

// ---- prep: z -> fragment-ordered (hi,lo) f16, scale 2^4 ----
// aF chunk (qb32, kc): 1KB hi + 1KB lo; lane l = l5*32+l31 holds row
// qb32*32+l31, k = kc*16 + l5*8 + j; 16B at chunk + l*8 halves.
__global__ void vq_prep_z(const float* __restrict__ z, _Float16* __restrict__ wsh) {
  int i = blockIdx.x * 256 + threadIdx.x;   // 1,048,576 = 32768 rows x 32 segs
  int row = i >> 5;
  int kseg = i & 31;                         // 8-col segment
  float4 v0 = ((const float4*)z)[i * 2];
  float4 v1 = ((const float4*)z)[i * 2 + 1];
  float xs[8] = {v0.x, v0.y, v0.z, v0.w, v1.x, v1.y, v1.z, v1.w};
  half8 h, l;
#pragma unroll
  for (int j = 0; j < 8; ++j) {
    float s = xs[j] * 16.0f;
    _Float16 hj = (_Float16)s;
    h[j] = hj;
    l[j] = (_Float16)(s - (float)hj);
  }
  unsigned qb32 = (unsigned)(row >> 5), l31 = (unsigned)(row & 31);
  unsigned kc = (unsigned)(kseg >> 1), l5 = (unsigned)(kseg & 1);
  unsigned lane = l5 * 32 + l31;
  unsigned base = (qb32 * 16u + kc) * 1024u + lane * 8u;   // hl=0
  *(half8*)&wsh[base] = h;
  *(half8*)&wsh[base + 512] = l;                            // hl=1
}

// ---- prep: codebook -> fragment-ordered (hi,lo) f16, scale 2^15 ----
__global__ void vq_prep_cb(const float* __restrict__ cb, _Float16* __restrict__ wsh) {
  int i = blockIdx.x * 256 + threadIdx.x;   // 262,144 = 8192 codes x 32 segs
  int row = i >> 5;
  int kseg = i & 31;
  float4 v0 = ((const float4*)cb)[i * 2];
  float4 v1 = ((const float4*)cb)[i * 2 + 1];
  float xs[8] = {v0.x, v0.y, v0.z, v0.w, v1.x, v1.y, v1.z, v1.w};
  half8 h, l;
#pragma unroll
  for (int j = 0; j < 8; ++j) {
    float s = xs[j] * 32768.0f;
    _Float16 hj = (_Float16)s;
    h[j] = hj;
    l[j] = (_Float16)(s - (float)hj);
  }
  unsigned cb32 = (unsigned)(row >> 5), l31 = (unsigned)(row & 31);
  unsigned kc = (unsigned)(kseg >> 1), l5 = (unsigned)(kseg & 1);
  unsigned lane = l5 * 32 + l31;
  unsigned base = BF_OFF + (cb32 * 16u + kc) * 1024u + lane * 8u;
  *(half8*)&wsh[base] = h;
  *(half8*)&wsh[base + 512] = l;
}

// ---- prep: 2^19 * ||e||^2 per code (unscaled squares, matching ref) ----
__global__ void vq_cbs(const float* __restrict__ cb, float* __restrict__ cbs) {
  int w = threadIdx.x >> 6, lane = threadIdx.x & 63;
  int code = blockIdx.x * 4 + w;
  float4 v = ((const float4*)cb)[code * 64 + lane];
  float ss = v.x * v.x + v.y * v.y + v.z * v.z + v.w * v.w;
#pragma unroll
  for (int off = 1; off < 64; off <<= 1) ss += __shfl_xor(ss, off);
  if (lane == 0) cbs[code] = ss * 524288.0f;   // 2^19 = 2^4 * 2^15
}

// ---- main: streaming fragment GEMM + fused argmin, XCD-pinned splits ----
// split = blockIdx & 7 -> same-split blocks co-reside on one XCD; that
// split's 1MB B-slice stays L2-resident. Block: 4 waves share 64 q-rows;
// wave w owns cols w*128 of each 512-code ct-tile; ct = 2 tiles -> 1024
// codes per split. Wave tile 64x128 = 2x4 of 32x32x16, 3 hi/lo terms.
__global__ __launch_bounds__(256, 2)
void vq_main(const _Float16* __restrict__ ws, const float* __restrict__ cbs,
             unsigned long long* __restrict__ partials) {
  __shared__ unsigned long long red[4][64];

  const int tid = threadIdx.x;
  const int lane = tid & 63;
  const int w = tid >> 6;
  const int l31 = lane & 31;
  const int l5 = lane >> 5;
  const int split = blockIdx.x & 7;          // XCD-pinned code slice
  const int qb    = blockIdx.x >> 3;         // 512 q-blocks
  const unsigned qb32 = (unsigned)qb * 2u;   // + mt
  const int c0 = split * 1024;
  const unsigned laneoff = (unsigned)lane * 8u;

  unsigned long long run = ~0ull;

  for (int ct = 0; ct < 2; ++ct) {
    f32x16 acc[2][4];
#pragma unroll
    for (int mt = 0; mt < 2; ++mt)
#pragma unroll
      for (int nt = 0; nt < 4; ++nt)
#pragma unroll
        for (int r = 0; r < 16; ++r) acc[mt][nt][r] = 0.0f;

    const unsigned cb32b = (unsigned)(split * 32 + ct * 16 + w * 4);  // + nt

#pragma unroll 2
    for (int kc = 0; kc < 16; ++kc) {
      half8 ah[2], al[2];
#pragma unroll
      for (int mt = 0; mt < 2; ++mt) {
        const _Float16* p = ws + ((qb32 + mt) * 16u + kc) * 1024u + laneoff;
        ah[mt] = *(const half8*)p;
        al[mt] = *(const half8*)(p + 512);
      }
#pragma unroll
      for (int nt = 0; nt < 4; ++nt) {
        const _Float16* p =
            ws + BF_OFF + ((cb32b + nt) * 16u + kc) * 1024u + laneoff;
        half8 bh = *(const half8*)p;
        half8 bl = *(const half8*)(p + 512);
#pragma unroll
        for (int mt = 0; mt < 2; ++mt) {
          acc[mt][nt] = __builtin_amdgcn_mfma_f32_32x32x16_f16(
              ah[mt], bh, acc[mt][nt], 0, 0, 0);
          acc[mt][nt] = __builtin_amdgcn_mfma_f32_32x32x16_f16(
              ah[mt], bl, acc[mt][nt], 0, 0, 0);
          acc[mt][nt] = __builtin_amdgcn_mfma_f32_32x32x16_f16(
              al[mt], bh, acc[mt][nt], 0, 0, 0);
        }
      }
    }

    // ---- epilogue: dist = 2^19*cb_sq - 2*acc; argmin over wave's 128 cols
    const int colbase = c0 + ct * 512 + w * 128 + l31;
    float cbsv[4];
#pragma unroll
    for (int nt = 0; nt < 4; ++nt) cbsv[nt] = cbs[colbase + nt * 32];
#pragma unroll
    for (int mt = 0; mt < 2; ++mt)
#pragma unroll
      for (int r = 0; r < 16; ++r) {
        float d = fmaf(-2.0f, acc[mt][0][r], cbsv[0]);
        unsigned ci = (unsigned)colbase;
#pragma unroll
        for (int nt = 1; nt < 4; ++nt) {
          float dn = fmaf(-2.0f, acc[mt][nt][r], cbsv[nt]);
          if (dn < d) { d = dn; ci = (unsigned)(colbase + nt * 32); }
        }
#pragma unroll
        for (int off = 1; off < 32; off <<= 1) {
          float od = __shfl_xor(d, off);
          unsigned oc = __shfl_xor(ci, off);
          if (od < d || (od == d && oc < ci)) { d = od; ci = oc; }
        }
        if (l31 == 0) {
          int row = mt * 32 + (r & 3) + 8 * (r >> 2) + 4 * l5;  // C layout
          unsigned u = __float_as_uint(d);
          u = (u & 0x80000000u) ? ~u : (u | 0x80000000u);       // orderable
          red[w][row] = ((unsigned long long)u << 32) | ci;
        }
      }
    __syncthreads();
    if (tid < 64) {
      unsigned long long v0 = red[0][tid], v1 = red[1][tid];
      unsigned long long v2 = red[2][tid], v3 = red[3][tid];
      if (v1 < v0) v0 = v1;
      if (v3 < v2) v2 = v3;
      if (v2 < v0) v0 = v2;
      if (v0 < run) run = v0;   // ties -> lower code (code in low bits)
    }
    __syncthreads();
  }

  if (tid < 64)
    partials[(size_t)split * N_Q + qb * 64 + tid] = run;
}

// ---- final: combine 8 splits, write INT32 indices ----
__global__ void vq_final(const unsigned long long* __restrict__ partials,
                         int* __restrict__ out) {
  int i = blockIdx.x * 256 + threadIdx.x;
  unsigned long long m = partials[i];
#pragma unroll
  for (int s = 1; s < 8; ++s) {
    unsigned long long v = partials[(size_t)s * N_Q + i];
    if (v < m) m = v;   // equal dist -> lower code (code in low bits)
  }
  out[i] = (int)(unsigned)(m & 0xffffffffull);
}

extern "C" void kernel_launch(void* const* d_in, const int* in_sizes, int n_in,
                              void* d_out, int out_size, void* d_ws, size_t ws_size,
                              hipStream_t stream) {
  const float* z  = (const float*)d_in[0];   // [32,32,32,256] fp32
  const float* cb = (const float*)d_in[1];   // [8192,256] fp32
  _Float16* wsh = (_Float16*)d_ws;           // aF 32MB | bF 8MB | cbs | partials
  float* cbs = (float*)((char*)d_ws + (size_t)40 * 1024 * 1024);
  unsigned long long* partials =
      (unsigned long long*)((char*)d_ws + (size_t)40 * 1024 * 1024 + 65536);

  hipLaunchKernelGGL(vq_prep_z,  dim3(4096), dim3(256), 0, stream, z, wsh);
  hipLaunchKernelGGL(vq_prep_cb, dim3(1024), dim3(256), 0, stream, cb, wsh);
  hipLaunchKernelGGL(vq_cbs,     dim3(2048), dim3(256), 0, stream, cb, cbs);
  hipLaunchKernelGGL(vq_main,    dim3(4096), dim3(256), 0, stream,
                     (const _Float16*)wsh, cbs, partials);
  hipLaunchKernelGGL(vq_final,   dim3(128),  dim3(256), 0, stream,
                     partials, (int*)d_out);
}